// Round 5
// baseline (709.239 us; speedup 1.0000x reference)
//
#include <hip/hip_runtime.h>

#define TT 200
#define XD 65
#define ROWSTR (TT * XD)  // 13000

typedef _Float16 h2 __attribute__((ext_vector_type(2)));
typedef _Float16 half8 __attribute__((ext_vector_type(8)));
typedef float f32x4 __attribute__((ext_vector_type(4)));

#define MFMA16 __builtin_amdgcn_mfma_f32_16x16x32_f16

// ---- ws (global scratch) dword offsets: prepacked f16 B-fragment pools ----
#define GOFF_WXC 0
#define GOFF_WXV 8192
#define GOFF_WHC 16384
#define GOFF_WHV 24576
#define GOFF_SCC 32768
#define GOFF_SCV 34816
#define GOFF_SVV 36864
#define GOFF_SVC 38912
#define GOFF_PC0 40960
#define GOFF_PV0 43008
#define GOFF_PC1 45056
#define GOFF_PV1 46080
#define GTOT     47104

// ---- LDS dword offsets ----
#define L_WHC 0       // 8192 dw
#define L_WHV 8192    // 8192 dw
#define L_HC0 16384   // 128 dw tiles: [4 rows][64 f16] swizzled
#define L_HC1 16512
#define L_HV0 16640
#define L_HV1 16768
#define L_Y0C0 16896
#define L_Y0C1 17024
#define L_Y0V  17152
#define L_CK   17280  // 2 x 4 floats
#define L_PART 17288  // 16 floats
#define L_TOT  17304  // 69,216 B per block -> 2 blocks/CU

__device__ __forceinline__ unsigned pk(float lo, float hi) {
  union { h2 h; unsigned u; } c;
  c.h.x = (_Float16)lo;
  c.h.y = (_Float16)hi;
  return c.u;
}

__device__ __forceinline__ float fexp2(float x) {
#if __has_builtin(__builtin_amdgcn_exp2f)
  return __builtin_amdgcn_exp2f(x);
#else
  return __expf(x * 0.6931471805599453f);
#endif
}
__device__ __forceinline__ float frcp(float x) {
#if __has_builtin(__builtin_amdgcn_rcpf)
  return __builtin_amdgcn_rcpf(x);
#else
  return 1.0f / x;
#endif
}
__device__ __forceinline__ float sigm(float x) { return frcp(1.f + fexp2(x * -1.44269504f)); }
__device__ __forceinline__ float tanh_fast(float x) { return fmaf(2.f, sigm(2.f * x), -1.f); }
__device__ __forceinline__ float leaky(float x) { return x > 0.0f ? x : 0.3f * x; }
__device__ __forceinline__ f32x4 sp4(float v) { f32x4 r = {v, v, v, v}; return r; }

// XOR swizzle within a [4][128B] tile: byte ^= (row)<<4
__device__ __forceinline__ int swz(int b) { return b ^ ((b >> 3) & 0x70); }

// A-frag from 4-row tile: row = lane&3 (rows 4-15 duplicated -> ignored C rows)
__device__ __forceinline__ half8 lda4(const char* smc, int dwoff, int kh, int lane) {
  int byte = (lane & 3) * 128 + kh * 64 + ((lane >> 4) << 4);
  union { uint4 u; half8 h; } c;
  c.u = *(const uint4*)(smc + (dwoff << 2) + swz(byte));
  return c.h;
}
// B-frag from LDS pool
__device__ __forceinline__ half8 ldb(const unsigned* m, int n, int kh, int lane) {
  union { uint4 u; half8 h; } c;
  c.u = *(const uint4*)(m + (((n * 2 + kh) * 64 + lane) << 2));
  return c.h;
}
// B-frag from global ws pool
__device__ __forceinline__ half8 ldg8(const unsigned* ws, int off, int n, int kh, int lane) {
  union { uint4 u; half8 h; } c;
  c.u = *(const uint4*)(ws + off + (((n * 2 + kh) * 64 + lane) << 2));
  return c.h;
}
// build f16 A-frag (8 consecutive f32) from global
__device__ __forceinline__ half8 mk8(const float* p) {
  half8 r;
#pragma unroll
  for (int i = 0; i < 8; ++i) r[i] = (_Float16)p[i];
  return r;
}

// ---- prepack: f32 weights -> f16 B-fragment pools in ws ----
extern "C" __global__ void prepack(const float* __restrict__ Wxc, const float* __restrict__ Wxv,
                                   const float* __restrict__ Whc, const float* __restrict__ Whv,
                                   const float* __restrict__ Wscc, const float* __restrict__ Wscv,
                                   const float* __restrict__ Wsvv, const float* __restrict__ Wsvc,
                                   const float* __restrict__ Wpc0, const float* __restrict__ Wpv0,
                                   const float* __restrict__ Wpc1, const float* __restrict__ Wpv1,
                                   unsigned* __restrict__ wsout) {
  int idx = blockIdx.x * 256 + threadIdx.x;
  if (idx >= GTOT) return;
  const float* W; int base, ncol;
  if      (idx < GOFF_WXV) { W = Wxc;  base = GOFF_WXC; ncol = 256; }
  else if (idx < GOFF_WHC) { W = Wxv;  base = GOFF_WXV; ncol = 256; }
  else if (idx < GOFF_WHV) { W = Whc;  base = GOFF_WHC; ncol = 256; }
  else if (idx < GOFF_SCC) { W = Whv;  base = GOFF_WHV; ncol = 256; }
  else if (idx < GOFF_SCV) { W = Wscc; base = GOFF_SCC; ncol = 64; }
  else if (idx < GOFF_SVV) { W = Wscv; base = GOFF_SCV; ncol = 64; }
  else if (idx < GOFF_SVC) { W = Wsvv; base = GOFF_SVV; ncol = 64; }
  else if (idx < GOFF_PC0) { W = Wsvc; base = GOFF_SVC; ncol = 64; }
  else if (idx < GOFF_PV0) { W = Wpc0; base = GOFF_PC0; ncol = 64; }
  else if (idx < GOFF_PC1) { W = Wpv0; base = GOFF_PV0; ncol = 64; }
  else if (idx < GOFF_PV1) { W = Wpc1; base = GOFF_PC1; ncol = 32; }
  else                     { W = Wpv1; base = GOFF_PV1; ncol = 32; }
  int local = idx - base;
  int d = local & 3, lane = (local >> 2) & 63, nk = local >> 8;
  int kh = nk & 1, n = nk >> 1;
  int k0 = kh * 32 + ((lane >> 4) << 3) + (d << 1);
  int c = n * 16 + (lane & 15);
  wsout[idx] = pk(W[k0 * ncol + c], W[(k0 + 1) * ncol + c]);
}

// ---- fused RNN: 4 rows/block, 512 blocks, 4 waves, 2 blocks/CU ----
extern "C" __global__ void __launch_bounds__(256, 2)
rnn_mfma(const float* __restrict__ x,
         const float* __restrict__ bxc, const float* __restrict__ bxv,
         const float* __restrict__ bpc0, const float* __restrict__ bpc1,
         const float* __restrict__ Wfcc, const float* __restrict__ bfcc,
         const float* __restrict__ bpv0, const float* __restrict__ bpv1,
         const float* __restrict__ Wfcv, const float* __restrict__ bfcv,
         const unsigned* __restrict__ ws, float* __restrict__ out) {
  extern __shared__ unsigned sm[];
  char* smc = (char*)sm;
  float* smf = (float*)sm;
  const int tid = threadIdx.x;
  const int lane = tid & 63, wid = tid >> 6;
  const int l15 = lane & 15, l4 = lane >> 4;
  const int wq = wid;  // 4 waves: wave wq owns unit slice [16wq, 16wq+16)
  const int r0 = blockIdx.x * 4;

  // Whc|Whv pools -> LDS (contiguous in ws at dword 16384, 16384 dwords)
  for (int i = tid; i < 4096; i += 256)
    ((uint4*)sm)[i] = ((const uint4*)ws)[4096 + i];
  // zero tiles + CK + PART
  for (int i = tid; i < L_TOT - L_HC0; i += 256) sm[L_HC0 + i] = 0;
  // stage click(0) -> CK[0]
  if (wid == 3 && lane >= 32 && lane < 36)
    smf[L_CK + (lane - 32)] = x[(size_t)(r0 + lane - 32) * ROWSTR + 64];

  // ---- hoisted constants ----
  float bgc[4], bgv[4];
#pragma unroll
  for (int m = 0; m < 4; ++m) {
    bgc[m] = bxc[(wq + 4 * m) * 16 + l15];
    bgv[m] = bxv[(wq + 4 * m) * 16 + l15];
  }
  const float b0c = bpc0[16 * wq + l15];
  const float b0v = bpv0[16 * wq + l15];
  const float b1h = (wid < 2 ? bpc1 : bpv1)[16 * (wid & 1) + l15];
  const float wfh = (wid < 2 ? Wfcc : Wfcv)[16 * (wid & 1) + l15];
  const float bfc = bfcc[0], bfv = bfcv[0];

  // hoisted B-fragments (constant across steps)
  half8 wxcF[8], wxvF[8];
#pragma unroll
  for (int m = 0; m < 4; ++m) {
    wxcF[2 * m] = ldg8(ws, GOFF_WXC, wq + 4 * m, 0, lane);
    wxcF[2 * m + 1] = ldg8(ws, GOFF_WXC, wq + 4 * m, 1, lane);
    wxvF[2 * m] = ldg8(ws, GOFF_WXV, wq + 4 * m, 0, lane);
    wxvF[2 * m + 1] = ldg8(ws, GOFF_WXV, wq + 4 * m, 1, lane);
  }
  const half8 sccF0 = ldg8(ws, GOFF_SCC, wq, 0, lane), sccF1 = ldg8(ws, GOFF_SCC, wq, 1, lane);
  const half8 scvF0 = ldg8(ws, GOFF_SCV, wq, 0, lane), scvF1 = ldg8(ws, GOFF_SCV, wq, 1, lane);
  const half8 svvF0 = ldg8(ws, GOFF_SVV, wq, 0, lane), svvF1 = ldg8(ws, GOFF_SVV, wq, 1, lane);
  const half8 svcF0 = ldg8(ws, GOFF_SVC, wq, 0, lane), svcF1 = ldg8(ws, GOFF_SVC, wq, 1, lane);
  const half8 pc0F0 = ldg8(ws, GOFF_PC0, wq, 0, lane), pc0F1 = ldg8(ws, GOFF_PC0, wq, 1, lane);
  const half8 pv0F0 = ldg8(ws, GOFF_PV0, wq, 0, lane), pv0F1 = ldg8(ws, GOFF_PV0, wq, 1, lane);
  const int hoff = (wid < 2) ? GOFF_PC1 : GOFF_PV1;
  const half8 hdF0 = ldg8(ws, hoff, wid & 1, 0, lane), hdF1 = ldg8(ws, hoff, wid & 1, 1, lane);

  const float* xr = x + (size_t)(r0 + (lane & 3)) * ROWSTR;  // A-row stream (dup rows 4-15)
  half8 fe0 = mk8(xr + l4 * 8);        // feats(0), k in [l4*8, l4*8+8)
  half8 fe1 = mk8(xr + 32 + l4 * 8);   // k in [32+l4*8, ...)

  float st_c[4] = {0.f, 0.f, 0.f, 0.f}, st_v[4] = {0.f, 0.f, 0.f, 0.f};
  float hvold[4] = {0.f, 0.f, 0.f, 0.f};
  float fv[4], iv[4], ov[4], gvv[4], psv[4];
  float2* o2 = (float2*)out;
  const int col2 = (16 * wq + l15) * 2;  // byte col offset in tiles

  __syncthreads();

  for (int t = 0; t < TT; ++t) {
    const int tn = (t + 1 < TT) ? t + 1 : t;
    // out(t-2)
    if (wid == 3 && lane < 4 && t >= 2) {
      float pc = sigm(smf[L_PART + lane] + smf[L_PART + 4 + lane] + bfc);
      float pv = sigm(smf[L_PART + 8 + lane] + smf[L_PART + 12 + lane] + bfv);
      o2[(size_t)(r0 + lane) * TT + (t - 2)] = make_float2(pc, pv * pc);
    }
    const int hcur = (t & 1) ? L_HC1 : L_HC0;
    const int hnew = (t & 1) ? L_HC0 : L_HC1;
    const int hvcur = (t & 1) ? L_HV1 : L_HV0;
    const int hvnew = (t & 1) ? L_HV0 : L_HV1;
    const int y0w = (t & 1) ? L_Y0C1 : L_Y0C0;
    const int y0p = (t & 1) ? L_Y0C0 : L_Y0C1;

    // ================ Phase A ================
    half8 hc0 = lda4(smc, hcur, 0, lane), hc1 = lda4(smc, hcur, 1, lane);
    half8 hv0 = lda4(smc, hvcur, 0, lane), hv1 = lda4(smc, hvcur, 1, lane);

    f32x4 ac[4], av[4];
#pragma unroll
    for (int m = 0; m < 4; ++m) { ac[m] = sp4(bgc[m]); av[m] = sp4(bgv[m]); }
#pragma unroll
    for (int m = 0; m < 4; ++m) {
      const int n = wq + 4 * m;
      ac[m] = MFMA16(fe0, wxcF[2 * m], ac[m], 0, 0, 0);
      ac[m] = MFMA16(fe1, wxcF[2 * m + 1], ac[m], 0, 0, 0);
      ac[m] = MFMA16(hc0, ldb(sm + L_WHC, n, 0, lane), ac[m], 0, 0, 0);
      ac[m] = MFMA16(hc1, ldb(sm + L_WHC, n, 1, lane), ac[m], 0, 0, 0);
      av[m] = MFMA16(fe0, wxvF[2 * m], av[m], 0, 0, 0);
      av[m] = MFMA16(fe1, wxvF[2 * m + 1], av[m], 0, 0, 0);
      av[m] = MFMA16(hv0, ldb(sm + L_WHV, n, 0, lane), av[m], 0, 0, 0);
      av[m] = MFMA16(hv1, ldb(sm + L_WHV, n, 1, lane), av[m], 0, 0, 0);
    }
    f32x4 pscc = sp4(0.f), pscv = sp4(0.f), psvv = sp4(0.f), apv = sp4(b0v);
    pscc = MFMA16(hc0, sccF0, pscc, 0, 0, 0);
    pscc = MFMA16(hc1, sccF1, pscc, 0, 0, 0);
    pscv = MFMA16(hv0, scvF0, pscv, 0, 0, 0);
    pscv = MFMA16(hv1, scvF1, pscv, 0, 0, 0);
    psvv = MFMA16(hv0, svvF0, psvv, 0, 0, 0);
    psvv = MFMA16(hv1, svvF1, psvv, 0, 0, 0);
    apv = MFMA16(hv0, pv0F0, apv, 0, 0, 0);
    apv = MFMA16(hv1, pv0F1, apv, 0, 0, 0);

    {
      float4 gp4 = *(const float4*)&smf[L_CK + (((t + 1) & 1) << 2)];  // click(t-1)
#pragma unroll
      for (int q = 0; q < 4; ++q) {
        // c-side elementwise (valid on l4==0 lanes; others compute garbage, unwritten)
        float f = sigm(ac[0][q]), i = sigm(ac[1][q]), o = sigm(ac[2][q]);
        float gc = tanh_fast(ac[3][q]);
        float gp = ((&gp4.x)[q] >= 0.5f) ? 1.f : 0.f;
        float sh = tanh_fast((1.f - gp) * pscc[q] + gp * pscv[q]);
        float s = sh + i * gc + (1.f - gp) * (f * st_c[q]);
        st_c[q] = s;
        float hcn = o * tanh_fast(s);
        // v-side stashes
        fv[q] = sigm(av[0][q]);
        iv[q] = sigm(av[1][q]);
        ov[q] = sigm(av[2][q]);
        gvv[q] = tanh_fast(av[3][q]);
        psv[q] = psvv[q];
        if (l4 == 0) {
          *(_Float16*)(smc + (hnew << 2) + swz(q * 128 + col2)) = (_Float16)hcn;
          *(_Float16*)(smc + (L_Y0V << 2) + swz(q * 128 + col2)) = (_Float16)leaky(apv[q]);
        }
      }
    }
    __syncthreads();  // B1

    // ================ Phase B ================
    half8 hn0 = lda4(smc, hnew, 0, lane), hn1 = lda4(smc, hnew, 1, lane);
    f32x4 psvc = sp4(0.f), a0 = sp4(b0c);
    psvc = MFMA16(hn0, svcF0, psvc, 0, 0, 0);
    psvc = MFMA16(hn1, svcF1, psvc, 0, 0, 0);
    a0 = MFMA16(hn0, pc0F0, a0, 0, 0, 0);
    a0 = MFMA16(hn1, pc0F1, a0, 0, 0, 0);

    if (t >= 1) {  // heads(t-1): waves 0-1 pc1 on y0p, waves 2-3 pv1 on Y0V
      const int asrc = (wid < 2) ? y0p : L_Y0V;
      f32x4 a1 = sp4(b1h);
      a1 = MFMA16(lda4(smc, asrc, 0, lane), hdF0, a1, 0, 0, 0);
      a1 = MFMA16(lda4(smc, asrc, 1, lane), hdF1, a1, 0, 0, 0);
#pragma unroll
      for (int q = 0; q < 4; ++q) {
        float tq = leaky(a1[q]) * wfh;
        tq += __shfl_xor(tq, 1, 64);
        tq += __shfl_xor(tq, 2, 64);
        tq += __shfl_xor(tq, 4, 64);
        tq += __shfl_xor(tq, 8, 64);
        if (l15 == 0 && l4 == 0)
          smf[L_PART + ((wid < 2) ? 0 : 8) + (wid & 1) * 4 + q] = tq;
      }
    }
    {
      float4 g4 = *(const float4*)&smf[L_CK + ((t & 1) << 2)];  // click(t)
#pragma unroll
      for (int q = 0; q < 4; ++q) {
        float g = ((&g4.x)[q] >= 0.5f) ? 1.f : 0.f;
        float sh = tanh_fast(psv[q] + g * psvc[q]);
        float s = sh + (1.f - g) * st_v[q] + g * (fv[q] * st_v[q] + iv[q] * gvv[q]);
        st_v[q] = s;
        float hvn = (1.f - g) * hvold[q] + g * (ov[q] * tanh_fast(s));
        hvold[q] = hvn;
        if (l4 == 0) {
          *(_Float16*)(smc + (hvnew << 2) + swz(q * 128 + col2)) = (_Float16)hvn;
          *(_Float16*)(smc + (y0w << 2) + swz(q * 128 + col2)) = (_Float16)leaky(a0[q]);
        }
      }
    }
    // stage click(t+1)
    if (wid == 3 && lane >= 32 && lane < 36)
      smf[L_CK + (((t + 1) & 1) << 2) + (lane - 32)] =
          x[(size_t)(r0 + lane - 32) * ROWSTR + tn * XD + 64];
    // prefetch feats(t+1) into registers
    fe0 = mk8(xr + tn * XD + l4 * 8);
    fe1 = mk8(xr + tn * XD + 32 + l4 * 8);
    __syncthreads();  // B2
  }

  // ================ epilogue: out(198), out(199) ================
  if (wid == 3 && lane < 4) {
    float pc = sigm(smf[L_PART + lane] + smf[L_PART + 4 + lane] + bfc);
    float pv = sigm(smf[L_PART + 8 + lane] + smf[L_PART + 12 + lane] + bfv);
    o2[(size_t)(r0 + lane) * TT + (TT - 2)] = make_float2(pc, pv * pc);
  }
  {  // pv0(199): h_v(199) in L_HV0 (t=199 odd -> hvnew = L_HV0)
    f32x4 apv = sp4(b0v);
    apv = MFMA16(lda4(smc, L_HV0, 0, lane), pv0F0, apv, 0, 0, 0);
    apv = MFMA16(lda4(smc, L_HV0, 1, lane), pv0F1, apv, 0, 0, 0);
    if (l4 == 0) {
#pragma unroll
      for (int q = 0; q < 4; ++q)
        *(_Float16*)(smc + (L_Y0V << 2) + swz(q * 128 + col2)) = (_Float16)leaky(apv[q]);
    }
  }
  __syncthreads();
  {  // heads(199): y0c(199) in L_Y0C1
    const int asrc = (wid < 2) ? L_Y0C1 : L_Y0V;
    f32x4 a1 = sp4(b1h);
    a1 = MFMA16(lda4(smc, asrc, 0, lane), hdF0, a1, 0, 0, 0);
    a1 = MFMA16(lda4(smc, asrc, 1, lane), hdF1, a1, 0, 0, 0);
#pragma unroll
    for (int q = 0; q < 4; ++q) {
      float tq = leaky(a1[q]) * wfh;
      tq += __shfl_xor(tq, 1, 64);
      tq += __shfl_xor(tq, 2, 64);
      tq += __shfl_xor(tq, 4, 64);
      tq += __shfl_xor(tq, 8, 64);
      if (l15 == 0 && l4 == 0)
        smf[L_PART + ((wid < 2) ? 0 : 8) + (wid & 1) * 4 + q] = tq;
    }
  }
  __syncthreads();
  if (wid == 0 && lane < 4) {
    float pc = sigm(smf[L_PART + lane] + smf[L_PART + 4 + lane] + bfc);
    float pv = sigm(smf[L_PART + 8 + lane] + smf[L_PART + 12 + lane] + bfv);
    o2[(size_t)(r0 + lane) * TT + (TT - 1)] = make_float2(pc, pv * pc);
  }
}

extern "C" void kernel_launch(void* const* d_in, const int* in_sizes, int n_in,
                              void* d_out, int out_size, void* d_ws, size_t ws_size,
                              hipStream_t stream) {
  const float* x    = (const float*)d_in[0];
  const float* Wxc  = (const float*)d_in[1];
  const float* bxc  = (const float*)d_in[2];
  const float* Whc  = (const float*)d_in[3];
  const float* Wxv  = (const float*)d_in[4];
  const float* bxv  = (const float*)d_in[5];
  const float* Whv  = (const float*)d_in[6];
  const float* Wscc = (const float*)d_in[7];
  const float* Wscv = (const float*)d_in[8];
  const float* Wsvv = (const float*)d_in[9];
  const float* Wsvc = (const float*)d_in[10];
  const float* Wpc0 = (const float*)d_in[11];
  const float* bpc0 = (const float*)d_in[12];
  const float* Wpc1 = (const float*)d_in[13];
  const float* bpc1 = (const float*)d_in[14];
  const float* Wfcc = (const float*)d_in[15];
  const float* bfcc = (const float*)d_in[16];
  const float* Wpv0 = (const float*)d_in[17];
  const float* bpv0 = (const float*)d_in[18];
  const float* Wpv1 = (const float*)d_in[19];
  const float* bpv1 = (const float*)d_in[20];
  const float* Wfcv = (const float*)d_in[21];
  const float* bfcv = (const float*)d_in[22];
  float* out = (float*)d_out;
  unsigned* wsbuf = (unsigned*)d_ws;

  prepack<<<184, 256, 0, stream>>>(Wxc, Wxv, Whc, Whv, Wscc, Wscv, Wsvv, Wsvc,
                                   Wpc0, Wpv0, Wpc1, Wpv1, wsbuf);

  (void)hipFuncSetAttribute(reinterpret_cast<const void*>(rnn_mfma),
                            hipFuncAttributeMaxDynamicSharedMemorySize, L_TOT * 4);
  rnn_mfma<<<512, 256, L_TOT * 4, stream>>>(
      x, bxc, bxv, bpc0, bpc1, Wfcc, bfcc, bpv0, bpv1, Wfcv, bfcv, wsbuf, out);
}

// Round 6
// 403.150 us; speedup vs baseline: 1.7592x; 1.7592x over previous
//
#include <hip/hip_runtime.h>

#define TT 200
#define XD 65
#define ROWSTR (TT * XD)  // 13000

typedef _Float16 h2 __attribute__((ext_vector_type(2)));
typedef _Float16 half8 __attribute__((ext_vector_type(8)));
typedef float f32x4 __attribute__((ext_vector_type(4)));

#define MFMA16 __builtin_amdgcn_mfma_f32_16x16x32_f16

// ---- ws (global scratch) dword offsets: prepacked f16 B-fragment pools ----
#define GOFF_WXC 0
#define GOFF_WXV 8192
#define GOFF_WHC 16384
#define GOFF_WHV 24576
#define GOFF_SCC 32768
#define GOFF_SCV 34816
#define GOFF_SVV 36864
#define GOFF_SVC 38912
#define GOFF_PC0 40960
#define GOFF_PV0 43008
#define GOFF_PC1 45056
#define GOFF_PV1 46080
#define GTOT     47104

// ---- LDS dword offsets ----
#define L_WHC 0       // 8192 dw
#define L_WHV 8192    // 8192 dw
#define L_HC0 16384   // 512-dw tiles: [16 rows][64 f16] swizzled (rows 8-15 stay 0)
#define L_HC1 16896
#define L_HV0 17408
#define L_HV1 17920
#define L_Y0C0 18432
#define L_Y0C1 18944
#define L_Y0V  19456
#define L_CK   19968  // 2 x 8 floats (click double buffer)
#define L_PART 19984  // 32 floats
#define L_TOT  20016  // 80,064 B

__device__ __forceinline__ unsigned pk(float lo, float hi) {
  union { h2 h; unsigned u; } c;
  c.h.x = (_Float16)lo;
  c.h.y = (_Float16)hi;
  return c.u;
}

__device__ __forceinline__ float fexp2(float x) {
#if __has_builtin(__builtin_amdgcn_exp2f)
  return __builtin_amdgcn_exp2f(x);
#else
  return __expf(x * 0.6931471805599453f);
#endif
}
__device__ __forceinline__ float frcp(float x) {
#if __has_builtin(__builtin_amdgcn_rcpf)
  return __builtin_amdgcn_rcpf(x);
#else
  return 1.0f / x;
#endif
}
__device__ __forceinline__ float sigm(float x) { return frcp(1.f + fexp2(x * -1.44269504f)); }
__device__ __forceinline__ float tanh_fast(float x) {
  return fmaf(2.f, frcp(1.f + fexp2(x * -2.88539008f)), -1.f);
}
__device__ __forceinline__ float leaky(float x) { return x > 0.0f ? x : 0.3f * x; }
__device__ __forceinline__ f32x4 sp4(float v) { f32x4 r = {v, v, v, v}; return r; }

// XOR swizzle within a [16][128B] tile
__device__ __forceinline__ int swz(int b) { return b ^ ((b >> 3) & 0x70); }

// A-frag: row = lane&15 (rows 8-15 read zeros), k = kh*32 + 8*(lane>>4) + i
__device__ __forceinline__ half8 lda(const char* smc, int dwoff, int kh, int lane) {
  int byte = (lane & 15) * 128 + kh * 64 + ((lane >> 4) << 4);
  union { uint4 u; half8 h; } c;
  c.u = *(const uint4*)(smc + (dwoff << 2) + swz(byte));
  return c.h;
}
// B-frag from LDS pool
__device__ __forceinline__ half8 ldb(const unsigned* m, int n, int kh, int lane) {
  union { uint4 u; half8 h; } c;
  c.u = *(const uint4*)(m + (((n * 2 + kh) * 64 + lane) << 2));
  return c.h;
}
// B-frag from global ws pool
__device__ __forceinline__ half8 ldg8(const unsigned* ws, int off, int n, int kh, int lane) {
  union { uint4 u; half8 h; } c;
  c.u = *(const uint4*)(ws + off + (((n * 2 + kh) * 64 + lane) << 2));
  return c.h;
}

// ---- prepack: f32 weights -> f16 B-fragment pools in ws ----
extern "C" __global__ void prepack(const float* __restrict__ Wxc, const float* __restrict__ Wxv,
                                   const float* __restrict__ Whc, const float* __restrict__ Whv,
                                   const float* __restrict__ Wscc, const float* __restrict__ Wscv,
                                   const float* __restrict__ Wsvv, const float* __restrict__ Wsvc,
                                   const float* __restrict__ Wpc0, const float* __restrict__ Wpv0,
                                   const float* __restrict__ Wpc1, const float* __restrict__ Wpv1,
                                   unsigned* __restrict__ wsout) {
  int idx = blockIdx.x * 256 + threadIdx.x;
  if (idx >= GTOT) return;
  const float* W; int base, ncol;
  if      (idx < GOFF_WXV) { W = Wxc;  base = GOFF_WXC; ncol = 256; }
  else if (idx < GOFF_WHC) { W = Wxv;  base = GOFF_WXV; ncol = 256; }
  else if (idx < GOFF_WHV) { W = Whc;  base = GOFF_WHC; ncol = 256; }
  else if (idx < GOFF_SCC) { W = Whv;  base = GOFF_WHV; ncol = 256; }
  else if (idx < GOFF_SCV) { W = Wscc; base = GOFF_SCC; ncol = 64; }
  else if (idx < GOFF_SVV) { W = Wscv; base = GOFF_SCV; ncol = 64; }
  else if (idx < GOFF_SVC) { W = Wsvv; base = GOFF_SVV; ncol = 64; }
  else if (idx < GOFF_PC0) { W = Wsvc; base = GOFF_SVC; ncol = 64; }
  else if (idx < GOFF_PV0) { W = Wpc0; base = GOFF_PC0; ncol = 64; }
  else if (idx < GOFF_PC1) { W = Wpv0; base = GOFF_PV0; ncol = 64; }
  else if (idx < GOFF_PV1) { W = Wpc1; base = GOFF_PC1; ncol = 32; }
  else                     { W = Wpv1; base = GOFF_PV1; ncol = 32; }
  int local = idx - base;
  int d = local & 3, lane = (local >> 2) & 63, nk = local >> 8;
  int kh = nk & 1, n = nk >> 1;
  int k0 = kh * 32 + ((lane >> 4) << 3) + (d << 1);
  int c = n * 16 + (lane & 15);
  wsout[idx] = pk(W[k0 * ncol + c], W[(k0 + 1) * ncol + c]);
}

// One RNN step; parity constants compile-time via 2x-unrolled caller.
#define STEP(T, HCUR, HNEW, HVCUR, HVNEW, Y0W, Y0P, CKP, CKC, FC, FN)                         \
  {                                                                                           \
    if ((T) >= 2 && wid == 7 && lane < 8) {                                                   \
      float pc = sigm(smf[L_PART + lane] + smf[L_PART + 8 + lane] + bfc);                     \
      float pv = sigm(smf[L_PART + 16 + lane] + smf[L_PART + 24 + lane] + bfv);               \
      o2[(size_t)(r0 + lane) * TT + ((T) - 2)] = make_float2(pc, pv * pc);                    \
    }                                                                                         \
    half8 fe0, fe1;                                                                           \
    _Pragma("unroll") for (int i = 0; i < 8; ++i) {                                           \
      fe0[i] = (_Float16)FC[i];                                                               \
      fe1[i] = (_Float16)FC[8 + i];                                                           \
    }                                                                                         \
    half8 hv0 = lda(smc, HVCUR, 0, lane), hv1 = lda(smc, HVCUR, 1, lane);                     \
    if (cw) {                                                                                 \
      half8 hc0 = lda(smc, HCUR, 0, lane), hc1 = lda(smc, HCUR, 1, lane);                     \
      f32x4 a0_ = sp4(bgate[0]), a1_ = sp4(bgate[1]), a2_ = sp4(bgate[2]),                    \
            a3_ = sp4(bgate[3]);                                                              \
      __builtin_amdgcn_s_setprio(1);                                                          \
      a0_ = MFMA16(fe0, wxF[0], a0_, 0, 0, 0);                                                \
      a0_ = MFMA16(fe1, wxF[1], a0_, 0, 0, 0);                                                \
      a0_ = MFMA16(hc0, ldb(sm + L_WHC, wq, 0, lane), a0_, 0, 0, 0);                          \
      a0_ = MFMA16(hc1, ldb(sm + L_WHC, wq, 1, lane), a0_, 0, 0, 0);                          \
      a1_ = MFMA16(fe0, wxF[2], a1_, 0, 0, 0);                                                \
      a1_ = MFMA16(fe1, wxF[3], a1_, 0, 0, 0);                                                \
      a1_ = MFMA16(hc0, ldb(sm + L_WHC, wq + 4, 0, lane), a1_, 0, 0, 0);                      \
      a1_ = MFMA16(hc1, ldb(sm + L_WHC, wq + 4, 1, lane), a1_, 0, 0, 0);                      \
      a2_ = MFMA16(fe0, wxF[4], a2_, 0, 0, 0);                                                \
      a2_ = MFMA16(fe1, wxF[5], a2_, 0, 0, 0);                                                \
      a2_ = MFMA16(hc0, ldb(sm + L_WHC, wq + 8, 0, lane), a2_, 0, 0, 0);                      \
      a2_ = MFMA16(hc1, ldb(sm + L_WHC, wq + 8, 1, lane), a2_, 0, 0, 0);                      \
      a3_ = MFMA16(fe0, wxF[6], a3_, 0, 0, 0);                                                \
      a3_ = MFMA16(fe1, wxF[7], a3_, 0, 0, 0);                                                \
      a3_ = MFMA16(hc0, ldb(sm + L_WHC, wq + 12, 0, lane), a3_, 0, 0, 0);                     \
      a3_ = MFMA16(hc1, ldb(sm + L_WHC, wq + 12, 1, lane), a3_, 0, 0, 0);                     \
      f32x4 pscc = sp4(0.f), pscv = sp4(0.f);                                                 \
      pscc = MFMA16(hc0, fA0, pscc, 0, 0, 0);                                                 \
      pscc = MFMA16(hc1, fA1, pscc, 0, 0, 0);                                                 \
      pscv = MFMA16(hv0, fB0, pscv, 0, 0, 0);                                                 \
      pscv = MFMA16(hv1, fB1, pscv, 0, 0, 0);                                                 \
      __builtin_amdgcn_s_setprio(0);                                                          \
      if (l4 < 2) {                                                                           \
        float4 gp4 = *(const float4*)&smf[(CKP) + (l4 << 2)];                                 \
        _Pragma("unroll") for (int q = 0; q < 4; ++q) {                                       \
          bool gp = (&gp4.x)[q] >= 0.5f;                                                      \
          float f = sigm(a0_[q]), ii = sigm(a1_[q]), o = sigm(a2_[q]);                        \
          float gc = tanh_fast(a3_[q]);                                                       \
          float sh = tanh_fast(gp ? pscv[q] : pscc[q]);                                       \
          float s = sh + ii * gc + (gp ? 0.f : f * st[q]);                                    \
          st[q] = s;                                                                          \
          float hcn = o * tanh_fast(s);                                                       \
          *(_Float16*)(smc + ((HNEW) << 2) + swz((l4 * 4 + q) * 128 + col2)) = (_Float16)hcn; \
        }                                                                                     \
      }                                                                                       \
    } else {                                                                                  \
      f32x4 a0_ = sp4(bgate[0]), a1_ = sp4(bgate[1]), a2_ = sp4(bgate[2]),                    \
            a3_ = sp4(bgate[3]);                                                              \
      __builtin_amdgcn_s_setprio(1);                                                          \
      a0_ = MFMA16(fe0, wxF[0], a0_, 0, 0, 0);                                                \
      a0_ = MFMA16(fe1, wxF[1], a0_, 0, 0, 0);                                                \
      a0_ = MFMA16(hv0, ldb(sm + L_WHV, wq, 0, lane), a0_, 0, 0, 0);                          \
      a0_ = MFMA16(hv1, ldb(sm + L_WHV, wq, 1, lane), a0_, 0, 0, 0);                          \
      a1_ = MFMA16(fe0, wxF[2], a1_, 0, 0, 0);                                                \
      a1_ = MFMA16(fe1, wxF[3], a1_, 0, 0, 0);                                                \
      a1_ = MFMA16(hv0, ldb(sm + L_WHV, wq + 4, 0, lane), a1_, 0, 0, 0);                      \
      a1_ = MFMA16(hv1, ldb(sm + L_WHV, wq + 4, 1, lane), a1_, 0, 0, 0);                      \
      a2_ = MFMA16(fe0, wxF[4], a2_, 0, 0, 0);                                                \
      a2_ = MFMA16(fe1, wxF[5], a2_, 0, 0, 0);                                                \
      a2_ = MFMA16(hv0, ldb(sm + L_WHV, wq + 8, 0, lane), a2_, 0, 0, 0);                      \
      a2_ = MFMA16(hv1, ldb(sm + L_WHV, wq + 8, 1, lane), a2_, 0, 0, 0);                      \
      a3_ = MFMA16(fe0, wxF[6], a3_, 0, 0, 0);                                                \
      a3_ = MFMA16(fe1, wxF[7], a3_, 0, 0, 0);                                                \
      a3_ = MFMA16(hv0, ldb(sm + L_WHV, wq + 12, 0, lane), a3_, 0, 0, 0);                     \
      a3_ = MFMA16(hv1, ldb(sm + L_WHV, wq + 12, 1, lane), a3_, 0, 0, 0);                     \
      f32x4 psvv = sp4(0.f);                                                                  \
      psvv = MFMA16(hv0, fA0, psvv, 0, 0, 0);                                                 \
      psvv = MFMA16(hv1, fA1, psvv, 0, 0, 0);                                                 \
      __builtin_amdgcn_s_setprio(0);                                                          \
      if ((T) >= 1) {                                                                         \
        f32x4 apv = sp4(b0u);                                                                 \
        apv = MFMA16(hv0, fC0, apv, 0, 0, 0);                                                 \
        apv = MFMA16(hv1, fC1, apv, 0, 0, 0);                                                 \
        if (l4 < 2) {                                                                         \
          _Pragma("unroll") for (int q = 0; q < 4; ++q)                                       \
              *(_Float16*)(smc + (L_Y0V << 2) + swz((l4 * 4 + q) * 128 + col2)) =             \
                  (_Float16)leaky(apv[q]);                                                    \
        }                                                                                     \
      }                                                                                       \
      _Pragma("unroll") for (int q = 0; q < 4; ++q) {                                         \
        fvv[q] = sigm(a0_[q]);                                                                \
        ivv[q] = sigm(a1_[q]);                                                                \
        ovv[q] = sigm(a2_[q]);                                                                \
        gvv[q] = tanh_fast(a3_[q]);                                                           \
        psv[q] = psvv[q];                                                                     \
      }                                                                                       \
    }                                                                                         \
    {                                                                                         \
      const int tn_ = ((T) + 1 < TT) ? (T) + 1 : (TT - 1);                                    \
      _Pragma("unroll") for (int i = 0; i < 8; ++i) {                                         \
        FN[i] = xrp[tn_ * XD + xk + i];                                                       \
        FN[8 + i] = xrp[tn_ * XD + 32 + xk + i];                                              \
      }                                                                                       \
      if (wid == 0 && lane >= 32 && lane < 40)                                                \
        ckn = x[(size_t)(r0 + lane - 32) * ROWSTR + tn_ * XD + 64];                           \
    }                                                                                         \
    __syncthreads(); /* B1 */                                                                 \
    half8 hn0 = lda(smc, HNEW, 0, lane), hn1 = lda(smc, HNEW, 1, lane);                       \
    if (!cw) {                                                                                \
      f32x4 psvc = sp4(0.f);                                                                  \
      psvc = MFMA16(hn0, fB0, psvc, 0, 0, 0);                                                 \
      psvc = MFMA16(hn1, fB1, psvc, 0, 0, 0);                                                 \
      if (l4 < 2) {                                                                           \
        float4 g4 = *(const float4*)&smf[(CKC) + (l4 << 2)];                                  \
        _Pragma("unroll") for (int q = 0; q < 4; ++q) {                                       \
          bool g = (&g4.x)[q] >= 0.5f;                                                        \
          float sh = tanh_fast(g ? psv[q] + psvc[q] : psv[q]);                                \
          float s = sh + (g ? fvv[q] * st[q] + ivv[q] * gvv[q] : st[q]);                      \
          st[q] = s;                                                                          \
          float hvn = g ? ovv[q] * tanh_fast(s) : hvold[q];                                   \
          hvold[q] = hvn;                                                                     \
          *(_Float16*)(smc + ((HVNEW) << 2) + swz((l4 * 4 + q) * 128 + col2)) = (_Float16)hvn;\
        }                                                                                     \
      }                                                                                       \
    } else {                                                                                  \
      f32x4 ap = sp4(b0u);                                                                    \
      ap = MFMA16(hn0, fC0, ap, 0, 0, 0);                                                     \
      ap = MFMA16(hn1, fC1, ap, 0, 0, 0);                                                     \
      if (l4 < 2) {                                                                           \
        _Pragma("unroll") for (int q = 0; q < 4; ++q)                                         \
            *(_Float16*)(smc + ((Y0W) << 2) + swz((l4 * 4 + q) * 128 + col2)) =               \
                (_Float16)leaky(ap[q]);                                                       \
      }                                                                                       \
      if ((T) >= 1) {                                                                         \
        const int asrc = (wid < 2) ? (Y0P) : L_Y0V;                                           \
        f32x4 ah = sp4(b1h);                                                                  \
        ah = MFMA16(lda(smc, asrc, 0, lane), fD0, ah, 0, 0, 0);                               \
        ah = MFMA16(lda(smc, asrc, 1, lane), fD1, ah, 0, 0, 0);                               \
        _Pragma("unroll") for (int q = 0; q < 4; ++q) {                                       \
          float tq = leaky(ah[q]) * wfh;                                                      \
          tq += __shfl_xor(tq, 1, 64);                                                        \
          tq += __shfl_xor(tq, 2, 64);                                                        \
          tq += __shfl_xor(tq, 4, 64);                                                        \
          tq += __shfl_xor(tq, 8, 64);                                                        \
          if (l15 == 0 && l4 < 2)                                                             \
            smf[L_PART + ((wid < 2) ? 0 : 16) + (wid & 1) * 8 + (l4 * 4 + q)] = tq;           \
        }                                                                                     \
      }                                                                                       \
    }                                                                                         \
    if (wid == 0 && lane >= 32 && lane < 40) smf[(CKP) + (lane - 32)] = ckn;                  \
    __syncthreads(); /* B2 */                                                                 \
  }

// ---- fused RNN: 8 rows/block, 256 blocks, 8 waves, 2 barriers/step ----
extern "C" __global__ void __launch_bounds__(512, 1)
rnn_mfma(const float* __restrict__ x,
         const float* __restrict__ bxc, const float* __restrict__ bxv,
         const float* __restrict__ bpc0, const float* __restrict__ bpc1,
         const float* __restrict__ Wfcc, const float* __restrict__ bfcc,
         const float* __restrict__ bpv0, const float* __restrict__ bpv1,
         const float* __restrict__ Wfcv, const float* __restrict__ bfcv,
         const unsigned* __restrict__ ws, float* __restrict__ out) {
  extern __shared__ unsigned sm[];
  char* smc = (char*)sm;
  float* smf = (float*)sm;
  const int tid = threadIdx.x;
  const int lane = tid & 63, wid = tid >> 6;
  const int l15 = lane & 15, l4 = lane >> 4;
  const int wq = wid & 3;
  const bool cw = wid < 4;
  const int r0 = blockIdx.x * 8;

  // Whc|Whv pools -> LDS; zero tiles/ck/part
  for (int i = tid; i < 4096; i += 512) ((uint4*)sm)[i] = ((const uint4*)ws)[4096 + i];
  for (int i = tid; i < L_TOT - 16384; i += 512) sm[16384 + i] = 0;

  // per-wave constants
  float bgate[4];
#pragma unroll
  for (int m = 0; m < 4; ++m) bgate[m] = (cw ? bxc : bxv)[(wq + 4 * m) * 16 + l15];
  const float b0u = (cw ? bpc0 : bpv0)[16 * wq + l15];
  const float b1h = (wid < 2 ? bpc1 : bpv1)[16 * (wid & 1) + l15];
  const float wfh = (wid < 2 ? Wfcc : Wfcv)[16 * (wid & 1) + l15];
  const float bfc = bfcc[0], bfv = bfcv[0];

  // hoisted B-fragments
  half8 wxF[8];
#pragma unroll
  for (int m = 0; m < 4; ++m) {
    wxF[2 * m] = ldg8(ws, cw ? GOFF_WXC : GOFF_WXV, wq + 4 * m, 0, lane);
    wxF[2 * m + 1] = ldg8(ws, cw ? GOFF_WXC : GOFF_WXV, wq + 4 * m, 1, lane);
  }
  half8 fA0, fA1, fB0, fB1, fC0, fC1, fD0, fD1;
  if (cw) {
    fA0 = ldg8(ws, GOFF_SCC, wq, 0, lane); fA1 = ldg8(ws, GOFF_SCC, wq, 1, lane);
    fB0 = ldg8(ws, GOFF_SCV, wq, 0, lane); fB1 = ldg8(ws, GOFF_SCV, wq, 1, lane);
    fC0 = ldg8(ws, GOFF_PC0, wq, 0, lane); fC1 = ldg8(ws, GOFF_PC0, wq, 1, lane);
    const int hoff = (wid < 2) ? GOFF_PC1 : GOFF_PV1;
    fD0 = ldg8(ws, hoff, wid & 1, 0, lane); fD1 = ldg8(ws, hoff, wid & 1, 1, lane);
  } else {
    fA0 = ldg8(ws, GOFF_SVV, wq, 0, lane); fA1 = ldg8(ws, GOFF_SVV, wq, 1, lane);
    fB0 = ldg8(ws, GOFF_SVC, wq, 0, lane); fB1 = ldg8(ws, GOFF_SVC, wq, 1, lane);
    fC0 = ldg8(ws, GOFF_PV0, wq, 0, lane); fC1 = ldg8(ws, GOFF_PV0, wq, 1, lane);
    fD0 = fA0; fD1 = fA1;  // unused by v-waves
  }

  // click(0) -> CK slot0 (slot1 stays 0 => g(-1)=0)
  if (wid == 0 && lane >= 32 && lane < 40)
    smf[L_CK + (lane - 32)] = x[(size_t)(r0 + lane - 32) * ROWSTR + 64];

  // feats A-row stream: row = lane&7 (A rows 8-15 duplicate -> C rows unused)
  const float* xrp = x + (size_t)(r0 + (lane & 7)) * ROWSTR;
  const int xk = l4 * 8;
  float fx[16], fy[16];
#pragma unroll
  for (int i = 0; i < 8; ++i) {
    fx[i] = xrp[xk + i];
    fx[8 + i] = xrp[32 + xk + i];
  }

  float st[4] = {0.f, 0.f, 0.f, 0.f};     // s_c (c-waves) / s_v (v-waves)
  float hvold[4] = {0.f, 0.f, 0.f, 0.f};  // h_v regs (v-waves)
  float fvv[4], ivv[4], ovv[4], gvv[4], psv[4];
  float ckn = 0.f;
  const int col2 = (16 * wq + l15) * 2;
  float2* o2 = (float2*)out;

  __syncthreads();

  for (int t = 0; t < TT; t += 2) {
    STEP(t,     L_HC0, L_HC1, L_HV0, L_HV1, L_Y0C0, L_Y0C1, L_CK + 8, L_CK + 0, fx, fy)
    STEP(t + 1, L_HC1, L_HC0, L_HV1, L_HV0, L_Y0C1, L_Y0C0, L_CK + 0, L_CK + 8, fy, fx)
  }

  // ---- epilogue: out(198), out(199) ----
  if (wid == 7 && lane < 8) {
    float pc = sigm(smf[L_PART + lane] + smf[L_PART + 8 + lane] + bfc);
    float pv = sigm(smf[L_PART + 16 + lane] + smf[L_PART + 24 + lane] + bfv);
    o2[(size_t)(r0 + lane) * TT + (TT - 2)] = make_float2(pc, pv * pc);
  }
  if (!cw) {  // pv0(199): h_v(199) in L_HV0 (t=199 odd -> HVNEW = L_HV0)
    f32x4 apv = sp4(b0u);
    apv = MFMA16(lda(smc, L_HV0, 0, lane), fC0, apv, 0, 0, 0);
    apv = MFMA16(lda(smc, L_HV0, 1, lane), fC1, apv, 0, 0, 0);
    if (l4 < 2) {
#pragma unroll
      for (int q = 0; q < 4; ++q)
        *(_Float16*)(smc + (L_Y0V << 2) + swz((l4 * 4 + q) * 128 + col2)) =
            (_Float16)leaky(apv[q]);
    }
  }
  __syncthreads();
  if (cw) {  // heads(199): y0c(199) in L_Y0C1
    const int asrc = (wid < 2) ? L_Y0C1 : L_Y0V;
    f32x4 ah = sp4(b1h);
    ah = MFMA16(lda(smc, asrc, 0, lane), fD0, ah, 0, 0, 0);
    ah = MFMA16(lda(smc, asrc, 1, lane), fD1, ah, 0, 0, 0);
#pragma unroll
    for (int q = 0; q < 4; ++q) {
      float tq = leaky(ah[q]) * wfh;
      tq += __shfl_xor(tq, 1, 64);
      tq += __shfl_xor(tq, 2, 64);
      tq += __shfl_xor(tq, 4, 64);
      tq += __shfl_xor(tq, 8, 64);
      if (l15 == 0 && l4 < 2)
        smf[L_PART + ((wid < 2) ? 0 : 16) + (wid & 1) * 8 + (l4 * 4 + q)] = tq;
    }
  }
  __syncthreads();
  if (wid == 0 && lane < 8) {
    float pc = sigm(smf[L_PART + lane] + smf[L_PART + 8 + lane] + bfc);
    float pv = sigm(smf[L_PART + 16 + lane] + smf[L_PART + 24 + lane] + bfv);
    o2[(size_t)(r0 + lane) * TT + (TT - 1)] = make_float2(pc, pv * pc);
  }
}

extern "C" void kernel_launch(void* const* d_in, const int* in_sizes, int n_in,
                              void* d_out, int out_size, void* d_ws, size_t ws_size,
                              hipStream_t stream) {
  const float* x    = (const float*)d_in[0];
  const float* Wxc  = (const float*)d_in[1];
  const float* bxc  = (const float*)d_in[2];
  const float* Whc  = (const float*)d_in[3];
  const float* Wxv  = (const float*)d_in[4];
  const float* bxv  = (const float*)d_in[5];
  const float* Whv  = (const float*)d_in[6];
  const float* Wscc = (const float*)d_in[7];
  const float* Wscv = (const float*)d_in[8];
  const float* Wsvv = (const float*)d_in[9];
  const float* Wsvc = (const float*)d_in[10];
  const float* Wpc0 = (const float*)d_in[11];
  const float* bpc0 = (const float*)d_in[12];
  const float* Wpc1 = (const float*)d_in[13];
  const float* bpc1 = (const float*)d_in[14];
  const float* Wfcc = (const float*)d_in[15];
  const float* bfcc = (const float*)d_in[16];
  const float* Wpv0 = (const float*)d_in[17];
  const float* bpv0 = (const float*)d_in[18];
  const float* Wpv1 = (const float*)d_in[19];
  const float* bpv1 = (const float*)d_in[20];
  const float* Wfcv = (const float*)d_in[21];
  const float* bfcv = (const float*)d_in[22];
  float* out = (float*)d_out;
  unsigned* wsbuf = (unsigned*)d_ws;

  prepack<<<184, 256, 0, stream>>>(Wxc, Wxv, Whc, Whv, Wscc, Wscv, Wsvv, Wsvc,
                                   Wpc0, Wpv0, Wpc1, Wpv1, wsbuf);

  (void)hipFuncSetAttribute(reinterpret_cast<const void*>(rnn_mfma),
                            hipFuncAttributeMaxDynamicSharedMemorySize, L_TOT * 4);
  rnn_mfma<<<256, 512, L_TOT * 4, stream>>>(
      x, bxc, bxv, bpc0, bpc1, Wfcc, bfcc, bpv0, bpv1, Wfcv, bfcv, wsbuf, out);
}